// Round 2
// baseline (504.769 us; speedup 1.0000x reference)
//
#include <hip/hip_runtime.h>
#include <math.h>

// hybridDynamicSimNew: B=65536 cars, H=5 window, F=50 steps, one thread/car.
// Occupancy is structurally 1 wave/SIMD (1024 waves on 1024 SIMDs), so VGPRs
// are nearly free (<=512) and all latency hiding is ILP.
//
// R2 theory: R1 kernel read all 400 fc1 weights from LDS every step
// (100 x ds_read_b128 broadcast / wave / step on the shared per-CU LDS pipe
// = likely the binding pipe at 4 waves/CU). This version keeps fc1 rows
// k=0..15 (256 floats) in VGPRs, k=16..24 (144 floats) in LDS, and fc2/b1/b2
// (67 floats) hoisted to registers -> ~400 VGPRs (under the 450 no-spill
// line), per-step LDS cut ~5x. Divisions replaced by v_rcp (no fast-math in
// harness flags, so '/' is an exact multi-inst div); custom branchless atan.

__device__ __forceinline__ float fast_tanhf(float x) {
    // tanh(x) = 1 - 2/(exp2(x*2*log2e)+1); rcp is 1-ulp approx (fine: result
    // feeds *dt=0.01 accumulation).
    float e = __builtin_amdgcn_exp2f(x * 2.8853900817779268f);
    return 1.0f - 2.0f * __builtin_amdgcn_rcpf(e + 1.0f);
}

// sin(x) for |x| <= ~0.16 (tire model: |tC*atan| <= 0.1*pi/2). err < 1e-9.
__device__ __forceinline__ float sin_small(float x) {
    float x2 = x * x;
    return x * (1.0f + x2 * (-1.66666667e-1f + x2 * 8.33333338e-3f));
}

// full-range branchless atan, max err ~1.5e-6 rad (minimax deg-11 odd on
// [0,1] + reciprocal identity for |x|>1).
__device__ __forceinline__ float fatanf(float x) {
    float ax = fabsf(x);
    bool big = ax > 1.0f;
    float z  = big ? __builtin_amdgcn_rcpf(ax) : ax;
    float z2 = z * z;
    float p = fmaf(z2, -0.0117212f, 0.05265332f);
    p = fmaf(z2, p, -0.11643287f);
    p = fmaf(z2, p,  0.19354346f);
    p = fmaf(z2, p, -0.33262347f);
    p = fmaf(z2, p,  0.99997726f);
    float r = z * p;
    r = big ? (1.57079632679489662f - r) : r;
    return copysignf(r, x);
}

__global__ __launch_bounds__(256, 1)
void sim_kernel(const float* __restrict__ fs,   // (B,5,8)
                const float* __restrict__ act,  // (B,50,2)
                const float* __restrict__ w1,   // (16,25) row-major [o][k]
                const float* __restrict__ b1,   // (16)
                const float* __restrict__ w2,   // (3,16)
                const float* __restrict__ b2,   // (3)
                const float* __restrict__ prm,  // (10)
                const int*   __restrict__ rnnp, // (1)
                float* __restrict__ out)        // (B,50,8)
{
    // LDS holds only the fc1 tail rows k=16..24, transposed [k][o] so the 16
    // o-values per k are 4 consecutive float4 (uniform-address broadcast).
    __shared__ float sW1t[9 * 16];

    const int tid = threadIdx.x;
    if (tid < 144) {
        int o = tid & 15;
        int k = 16 + (tid >> 4);
        sW1t[tid] = w1[o * 25 + k];
    }
    __syncthreads();

    const int b = blockIdx.x * 256 + tid;

    // wave-uniform params
    const float lf = prm[0], lr = prm[1], mIz = prm[2];
    const float cm1 = prm[3], cm2 = prm[4], cr = prm[5], cd = prm[6];
    const float tB = prm[7], tC = prm[8], tD = prm[9];
    const int   rnn = rnnp[0];
    const float dt = 0.01f;
    const float PI = 3.14159265358979323846f;
    const float INV2PI = 0.15915494309189535f;
    const float TWOPI = 6.28318530717958647692f;

    // fc1 head rows k=0..15 in VGPRs: w1v linear copy of w1[0:400],
    // accessed as w1v[o*25+k] (static indices only -> register-promoted).
    float w1v[400];
    {
        const float4* w1p = reinterpret_cast<const float4*>(w1);
#pragma unroll
        for (int i = 0; i < 100; ++i) {
            float4 v = w1p[i];
            w1v[i * 4 + 0] = v.x; w1v[i * 4 + 1] = v.y;
            w1v[i * 4 + 2] = v.z; w1v[i * 4 + 3] = v.w;
        }
    }

    // fc2 / biases in registers (67 floats).
    float b1r[16];
#pragma unroll
    for (int o = 0; o < 16; ++o) b1r[o] = b1[o];
    float w2r[48];
#pragma unroll
    for (int i = 0; i < 48; ++i) w2r[i] = w2[i];
    const float b2r0 = b2[0], b2r1 = b2[1], b2r2 = b2[2];

    // ---- initial window (40 floats) ----
    float wf[40];
    const float4* fsp = reinterpret_cast<const float4*>(fs + (size_t)b * 40);
#pragma unroll
    for (int i = 0; i < 10; ++i) {
        float4 v = fsp[i];
        wf[i * 4 + 0] = v.x; wf[i * 4 + 1] = v.y;
        wf[i * 4 + 2] = v.z; wf[i * 4 + 3] = v.w;
    }

    // feat layout: [Vxh(0..4), Vyh(5..9), omega(10..14), thr(15..19), steer(20..24)]
    float feat[25];
#pragma unroll
    for (int t = 0; t < 5; ++t) {
        float ph = wf[t * 8 + 4];
        float ch = __cosf(ph), sh = __sinf(ph);
        float v1 = wf[t * 8 + 1], v3 = wf[t * 8 + 3];
        feat[t]      =  v1 * ch + v3 * sh;
        feat[5 + t]  = -v1 * sh + v3 * ch;
        feat[10 + t] = wf[t * 8 + 5];
        feat[15 + t] = wf[t * 8 + 6];
        feat[20 + t] = wf[t * 8 + 7];
    }

    float x   = wf[32];
    float y   = wf[34];
    float psi = wf[36];
    float c = __cosf(psi), s = __sinf(psi);

    const float4* ap = reinterpret_cast<const float4*>(act + (size_t)b * 100);
    float* outp = out + (size_t)b * 400;

    float4 acur = ap[0];

#pragma unroll 1
    for (int f2 = 0; f2 < 25; ++f2) {
        // Block LICM of the loop-invariant LDS weight reads (hoisting all
        // 144 floats would blow the register budget past the spill line).
        asm volatile("" ::: "memory");

        // prefetch next 2 steps' actions (~1 full iteration of cover)
        float4 anext = ap[(f2 < 24) ? (f2 + 1) : 24];

#pragma unroll
        for (int half = 0; half < 2; ++half) {
            const float a0 = half ? acur.z : acur.x;
            const float a1 = half ? acur.w : acur.y;

            // ---- physics on latest window entry ----
            const float throttle = feat[19];
            const float steering = feat[24];
            const float Vx = feat[4];   // latest1*c + latest3*s (maintained)
            const float Vy = feat[9];   // -latest1*s + latest3*c

            const float atr    = fatanf(Vy * __builtin_amdgcn_rcpf(Vx));
            const float slip_f = -atr + steering;
            const float slip_r = -atr;                 // atan(-Vy/Vx)
            const float laf = tD * sin_small(tC * fatanf(tB * slip_f));
            const float lar = tD * sin_small(tC * fatanf(tB * slip_r));

            const float st_s = __sinf(steering), st_c = __cosf(steering);
            const float fwd  = (cm1 - cm2 * Vx) * throttle - cr - cd * Vx * Vx;

            float Vx2   = Vx + (fwd - laf * st_s) * dt;
            float Vy2   = Vy + (lar + laf * st_c) * dt;
            float omega = mIz * (laf * lf * st_c - lar * lr) * dt;

            // ---- RNN correction (wave-uniform branch) ----
            if (rnn) {
                float y1[16];
#pragma unroll
                for (int o = 0; o < 16; ++o) y1[o] = b1r[o];
                // head: weights from VGPRs
#pragma unroll
                for (int k = 0; k < 16; ++k) {
                    const float fk = feat[k];
#pragma unroll
                    for (int o = 0; o < 16; ++o)
                        y1[o] = fmaf(fk, w1v[o * 25 + k], y1[o]);
                }
                // tail: weights broadcast from LDS (uniform b128 reads)
#pragma unroll
                for (int k = 16; k < 25; ++k) {
                    const float fk = feat[k];
                    const float4* sp =
                        reinterpret_cast<const float4*>(&sW1t[(k - 16) * 16]);
#pragma unroll
                    for (int q = 0; q < 4; ++q) {
                        float4 wv = sp[q];
                        y1[q * 4 + 0] = fmaf(fk, wv.x, y1[q * 4 + 0]);
                        y1[q * 4 + 1] = fmaf(fk, wv.y, y1[q * 4 + 1]);
                        y1[q * 4 + 2] = fmaf(fk, wv.z, y1[q * 4 + 2]);
                        y1[q * 4 + 3] = fmaf(fk, wv.w, y1[q * 4 + 3]);
                    }
                }
#pragma unroll
                for (int o = 0; o < 16; ++o) y1[o] = fast_tanhf(y1[o]);

                float z0 = b2r0, z1 = b2r1, z2 = b2r2;
#pragma unroll
                for (int k = 0; k < 16; ++k) {
                    z0 = fmaf(y1[k], w2r[k],      z0);
                    z1 = fmaf(y1[k], w2r[16 + k], z1);
                    z2 = fmaf(y1[k], w2r[32 + k], z2);
                }
                Vx2   += fast_tanhf(z0) * 5.0f * dt;
                Vy2   += fast_tanhf(z1) * 5.0f * dt;
                omega += fast_tanhf(z2) * 3.0f * dt;
            }

            // ---- global-frame update ----
            const float Vxg = Vx2 * c - Vy2 * s;
            const float Vyg = Vx2 * s + Vy2 * c;
            float pn = psi + omega * dt + PI;
            pn = pn - floorf(pn * INV2PI) * TWOPI - PI;

            x = x + Vxg * dt;
            y = y + Vyg * dt;

            // ---- store new_full (8 floats = 2x float4) ----
            float4 o0 = make_float4(x, Vxg, y, Vyg);
            float4 o1 = make_float4(pn, omega, a0, a1);
            reinterpret_cast<float4*>(outp)[0] = o0;
            reinterpret_cast<float4*>(outp)[1] = o1;
            outp += 8;

            // ---- advance state / shift feature window ----
            psi = pn;
            c = __cosf(pn);
            s = __sinf(pn);
#pragma unroll
            for (int j = 0; j < 5; ++j)
#pragma unroll
                for (int t = 0; t < 4; ++t)
                    feat[j * 5 + t] = feat[j * 5 + t + 1];
            feat[4]  =  Vxg * c + Vyg * s;
            feat[9]  = -Vxg * s + Vyg * c;
            feat[14] = omega;
            feat[19] = a0;
            feat[24] = a1;
        }
        acur = anext;
    }
}

extern "C" void kernel_launch(void* const* d_in, const int* in_sizes, int n_in,
                              void* d_out, int out_size, void* d_ws, size_t ws_size,
                              hipStream_t stream) {
    const float* fs  = (const float*)d_in[0];
    const float* act = (const float*)d_in[1];
    const float* w1  = (const float*)d_in[2];
    const float* b1  = (const float*)d_in[3];
    const float* w2  = (const float*)d_in[4];
    const float* b2  = (const float*)d_in[5];
    const float* prm = (const float*)d_in[6];
    const int*   rnn = (const int*)d_in[7];
    float* out = (float*)d_out;

    const int Bn = in_sizes[0] / 40;  // 65536
    dim3 grid(Bn / 256), block(256);
    hipLaunchKernelGGL(sim_kernel, grid, block, 0, stream,
                       fs, act, w1, b1, w2, b2, prm, rnn, out);
}

// Round 4
// 214.652 us; speedup vs baseline: 2.3516x; 2.3516x over previous
//
#include <hip/hip_runtime.h>
#include <math.h>

// hybridDynamicSimNew: B=65536 cars, H=5, F=50. One thread/car, 1 wave/SIMD
// (structural occupancy floor), so VGPRs are near-free (<=512) and all
// latency hiding is ILP.
//
// R4 = R3 with a staging-bug fix: LDS transpose-stage now strided over the
// 256-thread block (R3's `if (tid < 400)` left rows k=16..24 uninitialized).
// Core change vs R2 (measured 408us, VGPR_Count=44 -> alloca never promoted,
// per-step scratch reloads): fc1 weights as 25 named ext_vector_type(16)
// SSA values = guaranteed VGPR residency; GEMV = 25 vector FMAs (packable to
// v_pk_fma_f32). Wave-uniform fc2/b2/params -> SGPRs via readfirstlane.

typedef float f16v __attribute__((ext_vector_type(16)));

__device__ __forceinline__ float rfl(float x) {
    return __int_as_float(__builtin_amdgcn_readfirstlane(__float_as_int(x)));
}

__device__ __forceinline__ f16v splat16(float x) {
    f16v v;
#pragma unroll
    for (int i = 0; i < 16; ++i) v[i] = x;
    return v;
}

__device__ __forceinline__ float fast_tanhf(float x) {
    // tanh(x) = 1 - 2/(exp2(2x*log2e)+1); rcp approx fine (feeds *dt accum).
    float e = __builtin_amdgcn_exp2f(x * 2.8853900817779268f);
    return 1.0f - 2.0f * __builtin_amdgcn_rcpf(e + 1.0f);
}

// sin(x) for |x| <= ~0.16 (tire model: |tC*atan| <= 0.1*pi/2)
__device__ __forceinline__ float sin_small(float x) {
    float x2 = x * x;
    return x * (1.0f + x2 * (-1.66666667e-1f + x2 * 8.33333338e-3f));
}

// branchless full-range atan, max err ~1.5e-6 rad
__device__ __forceinline__ float fatanf(float x) {
    float ax = fabsf(x);
    bool big = ax > 1.0f;
    float z  = big ? __builtin_amdgcn_rcpf(ax) : ax;
    float z2 = z * z;
    float p = fmaf(z2, -0.0117212f, 0.05265332f);
    p = fmaf(z2, p, -0.11643287f);
    p = fmaf(z2, p,  0.19354346f);
    p = fmaf(z2, p, -0.33262347f);
    p = fmaf(z2, p,  0.99997726f);
    float r = z * p;
    r = big ? (1.57079632679489662f - r) : r;
    return copysignf(r, x);
}

__global__ __launch_bounds__(256, 1)
void sim_kernel(const float* __restrict__ fs,   // (B,5,8)
                const float* __restrict__ act,  // (B,50,2)
                const float* __restrict__ w1,   // (16,25) [o][k]
                const float* __restrict__ b1,   // (16)
                const float* __restrict__ w2,   // (3,16)
                const float* __restrict__ b2,   // (3)
                const float* __restrict__ prm,  // (10)
                const int*   __restrict__ rnnp, // (1)
                float* __restrict__ out)        // (B,50,8)
{
    __shared__ float sW1t[25 * 16];  // transposed: sW1t[k*16+o] = w1[o][k]

    const int tid = threadIdx.x;
    // strided stage: 400 elements, 256 threads (R3 bug: `if (tid<400)` left
    // elements 256..399 uninitialized)
    for (int i = tid; i < 400; i += 256) {
        int o = i & 15;
        int k = i >> 4;
        sW1t[i] = w1[o * 25 + k];
    }
    __syncthreads();

    const int b = blockIdx.x * 256 + tid;

    // issue per-thread global loads early (latency cover under prologue)
    const float4* fsp = reinterpret_cast<const float4*>(fs + (size_t)b * 40);
    const float4* ap  = reinterpret_cast<const float4*>(act + (size_t)b * 100);
    float4 acur = ap[0];

    float wf[40];
#pragma unroll
    for (int i = 0; i < 10; ++i) {
        float4 v = fsp[i];
        wf[i * 4 + 0] = v.x; wf[i * 4 + 1] = v.y;
        wf[i * 4 + 2] = v.z; wf[i * 4 + 3] = v.w;
    }

    // wave-uniform params -> SGPR
    const float lf = rfl(prm[0]), lr = rfl(prm[1]), mIz = rfl(prm[2]);
    const float cm1 = rfl(prm[3]), cm2 = rfl(prm[4]), cr = rfl(prm[5]);
    const float cd = rfl(prm[6]);
    const float tB = rfl(prm[7]), tC = rfl(prm[8]), tD = rfl(prm[9]);
    const int   rnn = __builtin_amdgcn_readfirstlane(rnnp[0]);
    const float dt = 0.01f;
    const float PI = 3.14159265358979323846f;
    const float INV2PI = 0.15915494309189535f;
    const float TWOPI = 6.28318530717958647692f;

    // fc2 weights + b2 -> SGPRs (named scalars via readfirstlane)
#define DECLW2(K) \
    float w2a_##K = rfl(w2[(K)]);      \
    float w2b_##K = rfl(w2[16 + (K)]); \
    float w2c_##K = rfl(w2[32 + (K)]);
    DECLW2(0) DECLW2(1) DECLW2(2) DECLW2(3)
    DECLW2(4) DECLW2(5) DECLW2(6) DECLW2(7)
    DECLW2(8) DECLW2(9) DECLW2(10) DECLW2(11)
    DECLW2(12) DECLW2(13) DECLW2(14) DECLW2(15)
    const float b2s0 = rfl(b2[0]), b2s1 = rfl(b2[1]), b2s2 = rfl(b2[2]);

    // b1 as one vector (16 VGPR)
    f16v b1v;
    {
        const float4* bp = reinterpret_cast<const float4*>(b1);
#pragma unroll
        for (int q = 0; q < 4; ++q) {
            float4 v = bp[q];
            b1v[4 * q + 0] = v.x; b1v[4 * q + 1] = v.y;
            b1v[4 * q + 2] = v.z; b1v[4 * q + 3] = v.w;
        }
    }

    // ---- initial feature window ----
    // feat: [Vxh(0..4), Vyh(5..9), omega(10..14), thr(15..19), steer(20..24)]
    float feat[25];
#pragma unroll
    for (int t = 0; t < 5; ++t) {
        float ph = wf[t * 8 + 4];
        float ch = __cosf(ph), sh = __sinf(ph);
        float v1 = wf[t * 8 + 1], v3 = wf[t * 8 + 3];
        feat[t]      =  v1 * ch + v3 * sh;
        feat[5 + t]  = -v1 * sh + v3 * ch;
        feat[10 + t] = wf[t * 8 + 5];
        feat[15 + t] = wf[t * 8 + 6];
        feat[20 + t] = wf[t * 8 + 7];
    }

    float x   = wf[32];
    float y   = wf[34];
    float psi = wf[36];
    float c = __cosf(psi), s = __sinf(psi);

    // ---- fc1 weights: 25 named SSA vectors (400 VGPR, no alloca) ----
    f16v wr0, wr1, wr2, wr3, wr4, wr5, wr6, wr7, wr8, wr9, wr10, wr11, wr12,
         wr13, wr14, wr15, wr16, wr17, wr18, wr19, wr20, wr21, wr22, wr23,
         wr24;
#define LOADROW(K)                                                          \
    {                                                                       \
        const float4* sp = reinterpret_cast<const float4*>(&sW1t[(K) * 16]);\
        _Pragma("unroll") for (int q = 0; q < 4; ++q) {                     \
            float4 v = sp[q];                                               \
            wr##K[4 * q + 0] = v.x; wr##K[4 * q + 1] = v.y;                 \
            wr##K[4 * q + 2] = v.z; wr##K[4 * q + 3] = v.w;                 \
        }                                                                   \
    }
    LOADROW(0) LOADROW(1) LOADROW(2) LOADROW(3) LOADROW(4)
    LOADROW(5) LOADROW(6) LOADROW(7) LOADROW(8) LOADROW(9)
    LOADROW(10) LOADROW(11) LOADROW(12) LOADROW(13) LOADROW(14)
    LOADROW(15) LOADROW(16) LOADROW(17) LOADROW(18) LOADROW(19)
    LOADROW(20) LOADROW(21) LOADROW(22) LOADROW(23) LOADROW(24)

    float* outp = out + (size_t)b * 400;

#pragma unroll 1
    for (int f2 = 0; f2 < 25; ++f2) {
        float4 anext = ap[(f2 < 24) ? (f2 + 1) : 24];

#pragma unroll
        for (int half = 0; half < 2; ++half) {
            const float a0 = half ? acur.z : acur.x;
            const float a1 = half ? acur.w : acur.y;

            // ---- physics ----
            const float throttle = feat[19];
            const float steering = feat[24];
            const float Vx = feat[4];
            const float Vy = feat[9];

            const float atr    = fatanf(Vy * __builtin_amdgcn_rcpf(Vx));
            const float slip_f = -atr + steering;
            const float slip_r = -atr;
            const float laf = tD * sin_small(tC * fatanf(tB * slip_f));
            const float lar = tD * sin_small(tC * fatanf(tB * slip_r));

            const float st_s = __sinf(steering), st_c = __cosf(steering);
            const float fwd  = (cm1 - cm2 * Vx) * throttle - cr - cd * Vx * Vx;

            float Vx2   = Vx + (fwd - laf * st_s) * dt;
            float Vy2   = Vy + (lar + laf * st_c) * dt;
            float omega = mIz * (laf * lf * st_c - lar * lr) * dt;

            // ---- RNN (wave-uniform branch) ----
            if (rnn) {
                f16v y1v = b1v;
#define GK(K) y1v = __builtin_elementwise_fma(wr##K, splat16(feat[(K)]), y1v);
                GK(0) GK(1) GK(2) GK(3) GK(4)
                GK(5) GK(6) GK(7) GK(8) GK(9)
                GK(10) GK(11) GK(12) GK(13) GK(14)
                GK(15) GK(16) GK(17) GK(18) GK(19)
                GK(20) GK(21) GK(22) GK(23) GK(24)
#undef GK
                float z0 = b2s0, z1 = b2s1, z2 = b2s2;
#define FC2(K)                                       \
                {                                    \
                    float t_ = fast_tanhf(y1v[(K)]); \
                    z0 = fmaf(t_, w2a_##K, z0);      \
                    z1 = fmaf(t_, w2b_##K, z1);      \
                    z2 = fmaf(t_, w2c_##K, z2);      \
                }
                FC2(0) FC2(1) FC2(2) FC2(3)
                FC2(4) FC2(5) FC2(6) FC2(7)
                FC2(8) FC2(9) FC2(10) FC2(11)
                FC2(12) FC2(13) FC2(14) FC2(15)
#undef FC2
                Vx2   += fast_tanhf(z0) * 5.0f * dt;
                Vy2   += fast_tanhf(z1) * 5.0f * dt;
                omega += fast_tanhf(z2) * 3.0f * dt;
            }

            // ---- global-frame update ----
            const float Vxg = Vx2 * c - Vy2 * s;
            const float Vyg = Vx2 * s + Vy2 * c;
            float pn = psi + omega * dt + PI;
            pn = pn - floorf(pn * INV2PI) * TWOPI - PI;

            x = x + Vxg * dt;
            y = y + Vyg * dt;

            float4 o0 = make_float4(x, Vxg, y, Vyg);
            float4 o1 = make_float4(pn, omega, a0, a1);
            reinterpret_cast<float4*>(outp)[0] = o0;
            reinterpret_cast<float4*>(outp)[1] = o1;
            outp += 8;

            // ---- advance / shift window ----
            psi = pn;
            c = __cosf(pn);
            s = __sinf(pn);
#pragma unroll
            for (int j = 0; j < 5; ++j)
#pragma unroll
                for (int t = 0; t < 4; ++t)
                    feat[j * 5 + t] = feat[j * 5 + t + 1];
            feat[4]  =  Vxg * c + Vyg * s;
            feat[9]  = -Vxg * s + Vyg * c;
            feat[14] = omega;
            feat[19] = a0;
            feat[24] = a1;
        }
        acur = anext;
    }
}

extern "C" void kernel_launch(void* const* d_in, const int* in_sizes, int n_in,
                              void* d_out, int out_size, void* d_ws, size_t ws_size,
                              hipStream_t stream) {
    const float* fs  = (const float*)d_in[0];
    const float* act = (const float*)d_in[1];
    const float* w1  = (const float*)d_in[2];
    const float* b1  = (const float*)d_in[3];
    const float* w2  = (const float*)d_in[4];
    const float* b2  = (const float*)d_in[5];
    const float* prm = (const float*)d_in[6];
    const int*   rnn = (const int*)d_in[7];
    float* out = (float*)d_out;

    const int Bn = in_sizes[0] / 40;  // 65536
    dim3 grid(Bn / 256), block(256);
    hipLaunchKernelGGL(sim_kernel, grid, block, 0, stream,
                       fs, act, w1, b1, w2, b2, prm, rnn, out);
}